// Round 1
// baseline (1701.166 us; speedup 1.0000x reference)
//
#include <hip/hip_runtime.h>

#define N_NODES 100000
#define N_EDGES 1600000
#define E_TOT   (N_EDGES + N_NODES)   // 1,700,000 incl. self-loops
#define NEG_SLOPE 0.2f

// ---------------------------------------------------------------------------
// Layer 1 GEMM: xw1[n,j] = sum_k x[n,k] * W1[k,j]   (F=128 -> 128, heads=4,C=32)
// Fused: al1[n,h] = sum_c xw1[n,h,c]*a_src1[h,c], ar1 likewise.
// One block per node, 128 threads (one per output feature).
// ---------------------------------------------------------------------------
__global__ __launch_bounds__(128)
void k_gemm1(const float* __restrict__ x, const float* __restrict__ W1,
             const float* __restrict__ a_src1, const float* __restrict__ a_dst1,
             float* __restrict__ xw1, float* __restrict__ al1, float* __restrict__ ar1) {
    const int n = blockIdx.x;
    const int j = threadIdx.x;           // 0..127, head h = j>>5
    __shared__ float sx[128];
    sx[j] = x[n * 128 + j];
    __syncthreads();
    float acc = 0.f;
#pragma unroll 8
    for (int k = 0; k < 128; ++k)
        acc = fmaf(sx[k], W1[k * 128 + j], acc);   // coalesced over j
    xw1[n * 128 + j] = acc;

    __shared__ float ps[128], pd[128];
    ps[j] = acc * a_src1[j];             // a_src1 flat [4*32] matches j=h*32+c
    pd[j] = acc * a_dst1[j];
    __syncthreads();
    if (j < 4) {
        float s = 0.f, d = 0.f;
#pragma unroll
        for (int c = 0; c < 32; ++c) { s += ps[j * 32 + c]; d += pd[j * 32 + c]; }
        al1[n * 4 + j] = s;
        ar1[n * 4 + j] = d;
    }
}

// ---------------------------------------------------------------------------
// Layer 1 softmax denominator: denom1[d,h] += exp(leaky(al1[s,h]+ar1[d,h]))
// One thread per edge (4 heads each). Self-loops are virtual edges e>=N_EDGES.
// ---------------------------------------------------------------------------
__global__ __launch_bounds__(256)
void k_denom1(const int* __restrict__ ei, const float* __restrict__ al1,
              const float* __restrict__ ar1, float* __restrict__ denom1) {
    const int e = blockIdx.x * blockDim.x + threadIdx.x;
    if (e >= E_TOT) return;
    int s, d;
    if (e < N_EDGES) { s = ei[e]; d = ei[N_EDGES + e]; }
    else             { s = d = e - N_EDGES; }
    const float4 al = ((const float4*)al1)[s];
    const float4 ar = ((const float4*)ar1)[d];
    float v;
    v = al.x + ar.x; v = v > 0.f ? v : NEG_SLOPE * v; atomicAdd(&denom1[d * 4 + 0], expf(v));
    v = al.y + ar.y; v = v > 0.f ? v : NEG_SLOPE * v; atomicAdd(&denom1[d * 4 + 1], expf(v));
    v = al.z + ar.z; v = v > 0.f ? v : NEG_SLOPE * v; atomicAdd(&denom1[d * 4 + 2], expf(v));
    v = al.w + ar.w; v = v > 0.f ? v : NEG_SLOPE * v; atomicAdd(&denom1[d * 4 + 3], expf(v));
}

// ---------------------------------------------------------------------------
// Layer 1 weighted scatter: out1[d,j] += alpha[e,h] * xw1[s,j], j=h*32+c.
// 128 threads per edge (2 edges per 256-block).
// ---------------------------------------------------------------------------
__global__ __launch_bounds__(256)
void k_scatter1(const int* __restrict__ ei, const float* __restrict__ al1,
                const float* __restrict__ ar1, const float* __restrict__ denom1,
                const float* __restrict__ xw1, float* __restrict__ out1) {
    const int t = blockIdx.x * blockDim.x + threadIdx.x;
    const int e = t >> 7;
    const int j = t & 127;
    if (e >= E_TOT) return;
    int s, d;
    if (e < N_EDGES) { s = ei[e]; d = ei[N_EDGES + e]; }
    else             { s = d = e - N_EDGES; }
    const int h = j >> 5;
    float v = al1[s * 4 + h] + ar1[d * 4 + h];
    v = v > 0.f ? v : NEG_SLOPE * v;
    const float alpha = expf(v) / denom1[d * 4 + h];
    atomicAdd(&out1[d * 128 + j], alpha * xw1[s * 128 + j]);
}

// ---------------------------------------------------------------------------
// Layer 2 GEMM fused with layer-1 bias+ReLU:
//   h = relu(out1 + b1); xw2 = h @ W2 (128->16); al2/ar2 dots (heads=1).
// One block per node, 128 threads.
// ---------------------------------------------------------------------------
__global__ __launch_bounds__(128)
void k_gemm2(const float* __restrict__ out1, const float* __restrict__ b1,
             const float* __restrict__ W2, const float* __restrict__ a_src2,
             const float* __restrict__ a_dst2, float* __restrict__ xw2,
             float* __restrict__ al2, float* __restrict__ ar2) {
    const int n = blockIdx.x;
    const int j = threadIdx.x;           // 0..127
    __shared__ float sh[128];
    float hv = out1[n * 128 + j] + b1[j];
    sh[j] = hv > 0.f ? hv : 0.f;
    __syncthreads();
    __shared__ float sxw[16];
    if (j < 16) {
        float acc = 0.f;
#pragma unroll 8
        for (int k = 0; k < 128; ++k)
            acc = fmaf(sh[k], W2[k * 16 + j], acc);
        sxw[j] = acc;
        xw2[n * 16 + j] = acc;
    }
    __syncthreads();
    if (j == 0) {
        float s = 0.f, d = 0.f;
#pragma unroll
        for (int c = 0; c < 16; ++c) { s += sxw[c] * a_src2[c]; d += sxw[c] * a_dst2[c]; }
        al2[n] = s;
        ar2[n] = d;
    }
}

// ---------------------------------------------------------------------------
// Layer 2 denominator (heads=1).
// ---------------------------------------------------------------------------
__global__ __launch_bounds__(256)
void k_denom2(const int* __restrict__ ei, const float* __restrict__ al2,
              const float* __restrict__ ar2, float* __restrict__ denom2) {
    const int e = blockIdx.x * blockDim.x + threadIdx.x;
    if (e >= E_TOT) return;
    int s, d;
    if (e < N_EDGES) { s = ei[e]; d = ei[N_EDGES + e]; }
    else             { s = d = e - N_EDGES; }
    float v = al2[s] + ar2[d];
    v = v > 0.f ? v : NEG_SLOPE * v;
    atomicAdd(&denom2[d], expf(v));
}

// ---------------------------------------------------------------------------
// Layer 2 weighted scatter into d_out: out[d,j] += alpha * xw2[s,j], 16 feats.
// 16 threads per edge (16 edges per 256-block).
// ---------------------------------------------------------------------------
__global__ __launch_bounds__(256)
void k_scatter2(const int* __restrict__ ei, const float* __restrict__ al2,
                const float* __restrict__ ar2, const float* __restrict__ denom2,
                const float* __restrict__ xw2, float* __restrict__ out) {
    const int t = blockIdx.x * blockDim.x + threadIdx.x;
    const int e = t >> 4;
    const int j = t & 15;
    if (e >= E_TOT) return;
    int s, d;
    if (e < N_EDGES) { s = ei[e]; d = ei[N_EDGES + e]; }
    else             { s = d = e - N_EDGES; }
    float v = al2[s] + ar2[d];
    v = v > 0.f ? v : NEG_SLOPE * v;
    const float alpha = expf(v) / denom2[d];
    atomicAdd(&out[d * 16 + j], alpha * xw2[s * 16 + j]);
}

// ---------------------------------------------------------------------------
// Final bias add.
// ---------------------------------------------------------------------------
__global__ __launch_bounds__(256)
void k_bias2(float* __restrict__ out, const float* __restrict__ b2) {
    const int i = blockIdx.x * blockDim.x + threadIdx.x;
    if (i >= N_NODES * 16) return;
    out[i] += b2[i & 15];
}

extern "C" void kernel_launch(void* const* d_in, const int* in_sizes, int n_in,
                              void* d_out, int out_size, void* d_ws, size_t ws_size,
                              hipStream_t stream) {
    const float* x      = (const float*)d_in[0];
    const int*   ei     = (const int*)d_in[1];
    const float* W1     = (const float*)d_in[2];
    const float* a_src1 = (const float*)d_in[3];
    const float* a_dst1 = (const float*)d_in[4];
    const float* b1     = (const float*)d_in[5];
    const float* W2     = (const float*)d_in[6];
    const float* a_src2 = (const float*)d_in[7];
    const float* a_dst2 = (const float*)d_in[8];
    const float* b2     = (const float*)d_in[9];
    float* out = (float*)d_out;

    // Workspace layout (floats). Zero-init region kept contiguous for one memset.
    float* ws     = (float*)d_ws;
    float* xw1    = ws;                                   // N*128
    float* al1    = xw1 + (size_t)N_NODES * 128;          // N*4
    float* ar1    = al1 + (size_t)N_NODES * 4;            // N*4
    float* xw2    = ar1 + (size_t)N_NODES * 4;            // N*16
    float* al2    = xw2 + (size_t)N_NODES * 16;           // N
    float* ar2    = al2 + (size_t)N_NODES;                // N
    float* denom1 = ar2 + (size_t)N_NODES;                // N*4   } zeroed
    float* out1   = denom1 + (size_t)N_NODES * 4;         // N*128 } zeroed
    float* denom2 = out1 + (size_t)N_NODES * 128;         // N     } zeroed

    const size_t zero_bytes = ((size_t)N_NODES * 4 + (size_t)N_NODES * 128 + N_NODES) * sizeof(float);
    hipMemsetAsync(denom1, 0, zero_bytes, stream);
    hipMemsetAsync(d_out, 0, (size_t)out_size * sizeof(float), stream);

    // Layer 1
    k_gemm1<<<N_NODES, 128, 0, stream>>>(x, W1, a_src1, a_dst1, xw1, al1, ar1);
    k_denom1<<<(E_TOT + 255) / 256, 256, 0, stream>>>(ei, al1, ar1, denom1);
    k_scatter1<<<(E_TOT * 128) / 256, 256, 0, stream>>>(ei, al1, ar1, denom1, xw1, out1);

    // Layer 2 (bias1+relu fused into gemm2)
    k_gemm2<<<N_NODES, 128, 0, stream>>>(out1, b1, W2, a_src2, a_dst2, xw2, al2, ar2);
    k_denom2<<<(E_TOT + 255) / 256, 256, 0, stream>>>(ei, al2, ar2, denom2);
    k_scatter2<<<(E_TOT * 16 + 255) / 256, 256, 0, stream>>>(ei, al2, ar2, denom2, xw2, out);
    k_bias2<<<(N_NODES * 16 + 255) / 256, 256, 0, stream>>>(out, b2);
}

// Round 2
// 729.584 us; speedup vs baseline: 2.3317x; 2.3317x over previous
//
#include <hip/hip_runtime.h>

#define N_NODES 100000
#define N_EDGES 1600000
#define E_TOT   (N_EDGES + N_NODES)   // 1,700,000 incl. self-loops
#define NEG_SLOPE 0.2f
#define NB1 ((N_NODES + 255) / 256)   // 391 scan blocks

// ---------------------------------------------------------------------------
// CSR-by-dst construction: histogram -> 3-kernel exclusive scan -> fill.
// Both GAT layers share the same graph, so we build it once per call.
// ---------------------------------------------------------------------------
__global__ __launch_bounds__(256)
void k_hist(const int* __restrict__ ei, int* __restrict__ deg) {
    const int e = blockIdx.x * blockDim.x + threadIdx.x;
    if (e >= E_TOT) return;
    const int d = (e < N_EDGES) ? ei[N_EDGES + e] : e - N_EDGES;
    atomicAdd(&deg[d], 1);
}

__global__ __launch_bounds__(256)
void k_scan1(const int* __restrict__ deg, int* __restrict__ part, int* __restrict__ bsums) {
    __shared__ int buf[256];
    const int t = threadIdx.x;
    const int i = blockIdx.x * 256 + t;
    int v = (i < N_NODES) ? deg[i] : 0;
    buf[t] = v;
    __syncthreads();
    for (int off = 1; off < 256; off <<= 1) {
        int add = (t >= off) ? buf[t - off] : 0;
        __syncthreads();
        buf[t] += add;
        __syncthreads();
    }
    if (i < N_NODES) part[i] = buf[t] - v;   // exclusive within block
    if (t == 255) bsums[blockIdx.x] = buf[255];
}

__global__ __launch_bounds__(512)
void k_scan2(int* __restrict__ bsums) {
    __shared__ int buf[512];
    const int t = threadIdx.x;
    int v = (t < NB1) ? bsums[t] : 0;
    buf[t] = v;
    __syncthreads();
    for (int off = 1; off < 512; off <<= 1) {
        int add = (t >= off) ? buf[t - off] : 0;
        __syncthreads();
        buf[t] += add;
        __syncthreads();
    }
    if (t < NB1) bsums[t] = buf[t] - v;      // exclusive block offsets
}

__global__ __launch_bounds__(256)
void k_scan3(int* __restrict__ offs, const int* __restrict__ bsums, int* __restrict__ cur) {
    const int i = blockIdx.x * blockDim.x + threadIdx.x;
    if (i >= N_NODES) return;
    const int o = offs[i] + bsums[i >> 8];
    offs[i] = o;
    cur[i] = o;
}

__global__ __launch_bounds__(256)
void k_fill(const int* __restrict__ ei, int* __restrict__ cur, int* __restrict__ ssrc) {
    const int e = blockIdx.x * blockDim.x + threadIdx.x;
    if (e >= E_TOT) return;
    int s, d;
    if (e < N_EDGES) { s = ei[e]; d = ei[N_EDGES + e]; }
    else             { s = d = e - N_EDGES; }
    const int pos = atomicAdd(&cur[d], 1);
    ssrc[pos] = s;
}

// ---------------------------------------------------------------------------
// Layer 1 GEMM: 4 nodes/block, 512 threads. xw1 = x@W1, fused al1/ar1 dots
// via intra-wave shuffle reduction over each 32-lane head group.
// ---------------------------------------------------------------------------
__global__ __launch_bounds__(512)
void k_gemm1(const float* __restrict__ x, const float* __restrict__ W1,
             const float* __restrict__ a_src1, const float* __restrict__ a_dst1,
             float* __restrict__ xw1, float* __restrict__ al1, float* __restrict__ ar1) {
    const int t = threadIdx.x;
    const int j = t & 127;
    const int ns = t >> 7;                   // 0..3
    const int node = blockIdx.x * 4 + ns;
    __shared__ float sx[4][128];
    sx[ns][j] = x[node * 128 + j];
    __syncthreads();
    float acc = 0.f;
#pragma unroll 8
    for (int k = 0; k < 128; ++k)
        acc = fmaf(sx[ns][k], W1[k * 128 + j], acc);   // wave-broadcast LDS + coalesced W1 (L1-hit across waves)
    xw1[node * 128 + j] = acc;

    float ps = acc * a_src1[j];
    float pd = acc * a_dst1[j];
#pragma unroll
    for (int o = 16; o; o >>= 1) { ps += __shfl_xor(ps, o, 64); pd += __shfl_xor(pd, o, 64); }
    if ((t & 31) == 0) {
        const int h = j >> 5;
        al1[node * 4 + h] = ps;
        ar1[node * 4 + h] = pd;
    }
}

// ---------------------------------------------------------------------------
// Layer 1 pull-aggregation: one block (128 thr) per dst node. No atomics,
// denominator folded (softmax normalization deferred to epilogue).
// Phase A: 128 (edge,head) pairs compute exp weights into LDS.
// Phase B: all threads accumulate weighted xw1 rows.
// Epilogue fuses +b1 and ReLU (layer-2 input is ready to use).
// ---------------------------------------------------------------------------
__global__ __launch_bounds__(128)
void k_aggr1(const int* __restrict__ ssrc, const int* __restrict__ offs,
             const int* __restrict__ deg, const float* __restrict__ al1,
             const float* __restrict__ ar1, const float* __restrict__ xw1,
             const float* __restrict__ b1, float* __restrict__ out1) {
    const int d = blockIdx.x;
    const int j = threadIdx.x;               // 0..127
    const int h = j >> 5;
    const int beg = offs[d];
    const int n = deg[d];
    __shared__ float w_s[128];               // 32 edges x 4 heads
    __shared__ int s_s[32];
    const float arh = ar1[d * 4 + (j & 3)];  // for phase A role (head = j&3)
    float acc = 0.f, dnm = 0.f;

    for (int base = 0; base < n; base += 32) {
        const int m = min(32, n - base);
        const int eL = j >> 2, hh = j & 3;
        __syncthreads();                     // protect w_s/s_s reuse
        if (eL < m) {
            const int s = ssrc[beg + base + eL];
            if (hh == 0) s_s[eL] = s;
            float v = al1[s * 4 + hh] + arh;
            v = v > 0.f ? v : NEG_SLOPE * v;
            w_s[eL * 4 + hh] = __expf(v);
        }
        __syncthreads();
#pragma unroll 4
        for (int e = 0; e < m; ++e) {
            const float w = w_s[e * 4 + h];  // broadcast
            const int s = s_s[e];            // broadcast
            acc = fmaf(w, xw1[s * 128 + j], acc);
            dnm += w;
        }
    }
    const float hv = acc / dnm + b1[j];
    out1[d * 128 + j] = hv > 0.f ? hv : 0.f;  // fused bias + ReLU
}

// ---------------------------------------------------------------------------
// Layer 2 GEMM: 16 nodes/block, 256 threads. W2 (8KB) + h-tile (8KB, padded)
// in LDS; al2/ar2 via 16-lane shuffle reduction.
// ---------------------------------------------------------------------------
__global__ __launch_bounds__(256)
void k_gemm2(const float* __restrict__ out1, const float* __restrict__ W2,
             const float* __restrict__ a_src2, const float* __restrict__ a_dst2,
             float* __restrict__ xw2, float* __restrict__ al2, float* __restrict__ ar2) {
    const int t = threadIdx.x;
    const int node0 = blockIdx.x * 16;
    __shared__ float sW[128 * 16];
    __shared__ float sh[16][129];            // +1 pad: kills 4-way bank conflict
    for (int i = t; i < 2048; i += 256) sW[i] = W2[i];
    for (int i = t; i < 2048; i += 256) {
        const int nn = i >> 7, kk = i & 127;
        sh[nn][kk] = out1[(node0 + nn) * 128 + kk];   // bias+relu already applied
    }
    __syncthreads();
    const int nn = t >> 4;                   // 0..15
    const int j = t & 15;
    float acc = 0.f;
#pragma unroll 8
    for (int k = 0; k < 128; ++k)
        acc = fmaf(sh[nn][k], sW[k * 16 + j], acc);
    xw2[(node0 + nn) * 16 + j] = acc;

    float ps = acc * a_src2[j];
    float pd = acc * a_dst2[j];
#pragma unroll
    for (int o = 8; o; o >>= 1) { ps += __shfl_xor(ps, o, 64); pd += __shfl_xor(pd, o, 64); }
    if (j == 0) { al2[node0 + nn] = ps; ar2[node0 + nn] = pd; }
}

// ---------------------------------------------------------------------------
// Layer 2 pull-aggregation: 16 nodes/block, 16 threads per node. Redundant
// per-lane exp (cheap), fused +b2. Writes d_out exactly once per element.
// ---------------------------------------------------------------------------
__global__ __launch_bounds__(256)
void k_aggr2(const int* __restrict__ ssrc, const int* __restrict__ offs,
             const int* __restrict__ deg, const float* __restrict__ al2,
             const float* __restrict__ ar2, const float* __restrict__ xw2,
             const float* __restrict__ b2, float* __restrict__ out) {
    const int t = threadIdx.x;
    const int node = blockIdx.x * 16 + (t >> 4);
    const int j = t & 15;
    const int beg = offs[node];
    const int n = deg[node];
    const float ard = ar2[node];
    float acc = 0.f, dnm = 0.f;
    for (int k = 0; k < n; ++k) {
        const int s = ssrc[beg + k];         // broadcast within 16-lane group
        float v = al2[s] + ard;
        v = v > 0.f ? v : NEG_SLOPE * v;
        const float w = __expf(v);
        acc = fmaf(w, xw2[s * 16 + j], acc);
        dnm += w;
    }
    out[node * 16 + j] = acc / dnm + b2[j];
}

extern "C" void kernel_launch(void* const* d_in, const int* in_sizes, int n_in,
                              void* d_out, int out_size, void* d_ws, size_t ws_size,
                              hipStream_t stream) {
    const float* x      = (const float*)d_in[0];
    const int*   ei     = (const int*)d_in[1];
    const float* W1     = (const float*)d_in[2];
    const float* a_src1 = (const float*)d_in[3];
    const float* a_dst1 = (const float*)d_in[4];
    const float* b1     = (const float*)d_in[5];
    const float* W2     = (const float*)d_in[6];
    const float* a_src2 = (const float*)d_in[7];
    const float* a_dst2 = (const float*)d_in[8];
    const float* b2     = (const float*)d_in[9];
    float* out = (float*)d_out;

    // Workspace layout. xw1's region is dead after k_aggr1 and is reused for
    // xw2/al2/ar2 (written by k_gemm2, which only reads out1).
    float* ws   = (float*)d_ws;
    float* xw1  = ws;                                  // N*128
    float* out1 = xw1 + (size_t)N_NODES * 128;         // N*128
    float* al1  = out1 + (size_t)N_NODES * 128;        // N*4
    float* ar1  = al1 + (size_t)N_NODES * 4;           // N*4
    float* xw2  = xw1;                                 // N*16  (alias)
    float* al2  = xw1 + (size_t)N_NODES * 16;          // N     (alias)
    float* ar2  = xw1 + (size_t)N_NODES * 17;          // N     (alias)
    int* ideg = (int*)(ar1 + (size_t)N_NODES * 4);     // N
    int* ioff = ideg + N_NODES;                        // N
    int* icur = ioff + N_NODES;                        // N
    int* ibs  = icur + N_NODES;                        // 512 (scan block sums)
    int* isrc = ibs + 512;                             // E_TOT

    hipMemsetAsync(ideg, 0, (size_t)N_NODES * sizeof(int), stream);

    // CSR build (shared by both layers)
    k_hist<<<(E_TOT + 255) / 256, 256, 0, stream>>>(ei, ideg);
    k_scan1<<<NB1, 256, 0, stream>>>(ideg, ioff, ibs);
    k_scan2<<<1, 512, 0, stream>>>(ibs);
    k_scan3<<<NB1, 256, 0, stream>>>(ioff, ibs, icur);
    k_fill<<<(E_TOT + 255) / 256, 256, 0, stream>>>(ei, icur, isrc);

    // Layer 1
    k_gemm1<<<N_NODES / 4, 512, 0, stream>>>(x, W1, a_src1, a_dst1, xw1, al1, ar1);
    k_aggr1<<<N_NODES, 128, 0, stream>>>(isrc, ioff, ideg, al1, ar1, xw1, b1, out1);

    // Layer 2
    k_gemm2<<<N_NODES / 16, 256, 0, stream>>>(out1, W2, a_src2, a_dst2, xw2, al2, ar2);
    k_aggr2<<<N_NODES / 16, 256, 0, stream>>>(isrc, ioff, ideg, al2, ar2, xw2, b2, out);
}

// Round 3
// 571.109 us; speedup vs baseline: 2.9787x; 1.2775x over previous
//
#include <hip/hip_runtime.h>

#define N_NODES 100000
#define N_EDGES 1600000
#define E_TOT   (N_EDGES + N_NODES)   // 1,700,000 incl. self-loops
#define NEG_SLOPE 0.2f
#define NB1 ((N_NODES + 255) / 256)   // 391 scan blocks

// ---------------------------------------------------------------------------
// CSR-by-dst construction: histogram -> 3-kernel exclusive scan -> fill.
// ---------------------------------------------------------------------------
__global__ __launch_bounds__(256)
void k_hist(const int* __restrict__ ei, int* __restrict__ deg) {
    const int e = blockIdx.x * blockDim.x + threadIdx.x;
    if (e >= E_TOT) return;
    const int d = (e < N_EDGES) ? ei[N_EDGES + e] : e - N_EDGES;
    atomicAdd(&deg[d], 1);
}

__global__ __launch_bounds__(256)
void k_scan1(const int* __restrict__ deg, int* __restrict__ part, int* __restrict__ bsums) {
    __shared__ int buf[256];
    const int t = threadIdx.x;
    const int i = blockIdx.x * 256 + t;
    int v = (i < N_NODES) ? deg[i] : 0;
    buf[t] = v;
    __syncthreads();
    for (int off = 1; off < 256; off <<= 1) {
        int add = (t >= off) ? buf[t - off] : 0;
        __syncthreads();
        buf[t] += add;
        __syncthreads();
    }
    if (i < N_NODES) part[i] = buf[t] - v;   // exclusive within block
    if (t == 255) bsums[blockIdx.x] = buf[255];
}

__global__ __launch_bounds__(512)
void k_scan2(int* __restrict__ bsums) {
    __shared__ int buf[512];
    const int t = threadIdx.x;
    int v = (t < NB1) ? bsums[t] : 0;
    buf[t] = v;
    __syncthreads();
    for (int off = 1; off < 512; off <<= 1) {
        int add = (t >= off) ? buf[t - off] : 0;
        __syncthreads();
        buf[t] += add;
        __syncthreads();
    }
    if (t < NB1) bsums[t] = buf[t] - v;      // exclusive block offsets
}

__global__ __launch_bounds__(256)
void k_scan3(int* __restrict__ offs, const int* __restrict__ bsums, int* __restrict__ cur) {
    const int i = blockIdx.x * blockDim.x + threadIdx.x;
    if (i >= N_NODES) return;
    const int o = offs[i] + bsums[i >> 8];
    offs[i] = o;
    cur[i] = o;
}

__global__ __launch_bounds__(256)
void k_fill(const int* __restrict__ ei, int* __restrict__ cur, int* __restrict__ ssrc) {
    const int e = blockIdx.x * blockDim.x + threadIdx.x;
    if (e >= E_TOT) return;
    int s, d;
    if (e < N_EDGES) { s = ei[e]; d = ei[N_EDGES + e]; }
    else             { s = d = e - N_EDGES; }
    const int pos = atomicAdd(&cur[d], 1);
    ssrc[pos] = s;
}

// ---------------------------------------------------------------------------
// Layer 1 GEMM, register-tiled: 256 threads, 32 nodes/block. Each thread owns
// a 4-node x 4-col tile (16 accumulators) -> each LDS operand feeds 4 FMAs.
// W1 staged k-tile-wise in LDS: W1 global traffic = 64KB/block (one pass).
// Fused al1/ar1 attention dots via 8-lane shuffle reduction.
// ---------------------------------------------------------------------------
__global__ __launch_bounds__(256)
void k_gemm1(const float* __restrict__ x, const float* __restrict__ W1,
             const float* __restrict__ a_src1, const float* __restrict__ a_dst1,
             float* __restrict__ xw1, float* __restrict__ al1, float* __restrict__ ar1) {
    const int t = threadIdx.x;
    const int n0 = blockIdx.x * 32;
    __shared__ float sx[32][128];   // 16 KB
    __shared__ float sW[32][128];   // 16 KB (one 32-row k-tile of W1)

    {   // stage x tile: 1024 float4s, coalesced
        const float4* xg = (const float4*)(x + (size_t)n0 * 128);
#pragma unroll
        for (int i = 0; i < 4; ++i) {
            const int f = t + i * 256;
            ((float4*)sx)[f] = xg[f];
        }
    }

    const int tj = t & 31;          // column group: cols 4*tj .. 4*tj+3
    const int tn = (t >> 5) * 4;    // node group:   nodes tn .. tn+3
    float4 acc[4] = {{0,0,0,0},{0,0,0,0},{0,0,0,0},{0,0,0,0}};

    for (int kt = 0; kt < 128; kt += 32) {
        __syncthreads();            // sx ready (first iter) / sW drained (later)
        const float4* wg = (const float4*)(W1 + (size_t)kt * 128);
#pragma unroll
        for (int i = 0; i < 4; ++i) {
            const int f = t + i * 256;
            ((float4*)sW)[f] = wg[f];
        }
        __syncthreads();
        for (int k = 0; k < 32; k += 4) {
            float4 xv[4];
#pragma unroll
            for (int i = 0; i < 4; ++i)
                xv[i] = *(const float4*)&sx[tn + i][kt + k];   // broadcast reads
#pragma unroll
            for (int kk = 0; kk < 4; ++kk) {
                const float4 wv = *(const float4*)&sW[k + kk][tj * 4];
#pragma unroll
                for (int i = 0; i < 4; ++i) {
                    const float xs = ((const float*)&xv[i])[kk];
                    acc[i].x = fmaf(xs, wv.x, acc[i].x);
                    acc[i].y = fmaf(xs, wv.y, acc[i].y);
                    acc[i].z = fmaf(xs, wv.z, acc[i].z);
                    acc[i].w = fmaf(xs, wv.w, acc[i].w);
                }
            }
        }
    }

    // write xw1 (each tn-group of 32 lanes covers one contiguous 512B row)
#pragma unroll
    for (int i = 0; i < 4; ++i)
        *(float4*)&xw1[(size_t)(n0 + tn + i) * 128 + tj * 4] = acc[i];

    // fused attention dots: head h = tj>>3 (cols 4tj..4tj+3 never cross a head)
    const float4 asv = ((const float4*)a_src1)[tj];
    const float4 adv = ((const float4*)a_dst1)[tj];
#pragma unroll
    for (int i = 0; i < 4; ++i) {
        float ps = acc[i].x * asv.x + acc[i].y * asv.y + acc[i].z * asv.z + acc[i].w * asv.w;
        float pd = acc[i].x * adv.x + acc[i].y * adv.y + acc[i].z * adv.z + acc[i].w * adv.w;
#pragma unroll
        for (int o = 1; o < 8; o <<= 1) { ps += __shfl_xor(ps, o, 64); pd += __shfl_xor(pd, o, 64); }
        if ((tj & 7) == 0) {
            const int h = tj >> 3;
            al1[(size_t)(n0 + tn + i) * 4 + h] = ps;
            ar1[(size_t)(n0 + tn + i) * 4 + h] = pd;
        }
    }
}

// ---------------------------------------------------------------------------
// Layer 1 pull-aggregation: one block (128 thr) per dst node. No atomics.
// ---------------------------------------------------------------------------
__global__ __launch_bounds__(128)
void k_aggr1(const int* __restrict__ ssrc, const int* __restrict__ offs,
             const int* __restrict__ deg, const float* __restrict__ al1,
             const float* __restrict__ ar1, const float* __restrict__ xw1,
             const float* __restrict__ b1, float* __restrict__ out1) {
    const int d = blockIdx.x;
    const int j = threadIdx.x;               // 0..127
    const int h = j >> 5;
    const int beg = offs[d];
    const int n = deg[d];
    __shared__ float w_s[128];               // 32 edges x 4 heads
    __shared__ int s_s[32];
    const float arh = ar1[d * 4 + (j & 3)];  // for phase A role (head = j&3)
    float acc = 0.f, dnm = 0.f;

    for (int base = 0; base < n; base += 32) {
        const int m = min(32, n - base);
        const int eL = j >> 2, hh = j & 3;
        __syncthreads();                     // protect w_s/s_s reuse
        if (eL < m) {
            const int s = ssrc[beg + base + eL];
            if (hh == 0) s_s[eL] = s;
            float v = al1[s * 4 + hh] + arh;
            v = v > 0.f ? v : NEG_SLOPE * v;
            w_s[eL * 4 + hh] = __expf(v);
        }
        __syncthreads();
#pragma unroll 4
        for (int e = 0; e < m; ++e) {
            const float w = w_s[e * 4 + h];  // broadcast
            const int s = s_s[e];            // broadcast
            acc = fmaf(w, xw1[s * 128 + j], acc);
            dnm += w;
        }
    }
    const float hv = acc / dnm + b1[j];
    out1[d * 128 + j] = hv > 0.f ? hv : 0.f;  // fused bias + ReLU
}

// ---------------------------------------------------------------------------
// Layer 2 GEMM: 16 nodes/block, 256 threads.
// ---------------------------------------------------------------------------
__global__ __launch_bounds__(256)
void k_gemm2(const float* __restrict__ out1, const float* __restrict__ W2,
             const float* __restrict__ a_src2, const float* __restrict__ a_dst2,
             float* __restrict__ xw2, float* __restrict__ al2, float* __restrict__ ar2) {
    const int t = threadIdx.x;
    const int node0 = blockIdx.x * 16;
    __shared__ float sW[128 * 16];
    __shared__ float sh[16][129];            // +1 pad: kills 4-way bank conflict
    for (int i = t; i < 2048; i += 256) sW[i] = W2[i];
    for (int i = t; i < 2048; i += 256) {
        const int nn = i >> 7, kk = i & 127;
        sh[nn][kk] = out1[(node0 + nn) * 128 + kk];   // bias+relu already applied
    }
    __syncthreads();
    const int nn = t >> 4;                   // 0..15
    const int j = t & 15;
    float acc = 0.f;
#pragma unroll 8
    for (int k = 0; k < 128; ++k)
        acc = fmaf(sh[nn][k], sW[k * 16 + j], acc);
    xw2[(node0 + nn) * 16 + j] = acc;

    float ps = acc * a_src2[j];
    float pd = acc * a_dst2[j];
#pragma unroll
    for (int o = 8; o; o >>= 1) { ps += __shfl_xor(ps, o, 64); pd += __shfl_xor(pd, o, 64); }
    if (j == 0) { al2[node0 + nn] = ps; ar2[node0 + nn] = pd; }
}

// ---------------------------------------------------------------------------
// Layer 2 pull-aggregation: 16 nodes/block, 16 threads per node.
// ---------------------------------------------------------------------------
__global__ __launch_bounds__(256)
void k_aggr2(const int* __restrict__ ssrc, const int* __restrict__ offs,
             const int* __restrict__ deg, const float* __restrict__ al2,
             const float* __restrict__ ar2, const float* __restrict__ xw2,
             const float* __restrict__ b2, float* __restrict__ out) {
    const int t = threadIdx.x;
    const int node = blockIdx.x * 16 + (t >> 4);
    const int j = t & 15;
    const int beg = offs[node];
    const int n = deg[node];
    const float ard = ar2[node];
    float acc = 0.f, dnm = 0.f;
    for (int k = 0; k < n; ++k) {
        const int s = ssrc[beg + k];         // broadcast within 16-lane group
        float v = al2[s] + ard;
        v = v > 0.f ? v : NEG_SLOPE * v;
        const float w = __expf(v);
        acc = fmaf(w, xw2[s * 16 + j], acc);
        dnm += w;
    }
    out[node * 16 + j] = acc / dnm + b2[j];
}

extern "C" void kernel_launch(void* const* d_in, const int* in_sizes, int n_in,
                              void* d_out, int out_size, void* d_ws, size_t ws_size,
                              hipStream_t stream) {
    const float* x      = (const float*)d_in[0];
    const int*   ei     = (const int*)d_in[1];
    const float* W1     = (const float*)d_in[2];
    const float* a_src1 = (const float*)d_in[3];
    const float* a_dst1 = (const float*)d_in[4];
    const float* b1     = (const float*)d_in[5];
    const float* W2     = (const float*)d_in[6];
    const float* a_src2 = (const float*)d_in[7];
    const float* a_dst2 = (const float*)d_in[8];
    const float* b2     = (const float*)d_in[9];
    float* out = (float*)d_out;

    // Workspace layout. xw1's region is dead after k_aggr1 and is reused for
    // xw2/al2/ar2 (written by k_gemm2, which only reads out1).
    float* ws   = (float*)d_ws;
    float* xw1  = ws;                                  // N*128
    float* out1 = xw1 + (size_t)N_NODES * 128;         // N*128
    float* al1  = out1 + (size_t)N_NODES * 128;        // N*4
    float* ar1  = al1 + (size_t)N_NODES * 4;           // N*4
    float* xw2  = xw1;                                 // N*16  (alias)
    float* al2  = xw1 + (size_t)N_NODES * 16;          // N     (alias)
    float* ar2  = xw1 + (size_t)N_NODES * 17;          // N     (alias)
    int* ideg = (int*)(ar1 + (size_t)N_NODES * 4);     // N
    int* ioff = ideg + N_NODES;                        // N
    int* icur = ioff + N_NODES;                        // N
    int* ibs  = icur + N_NODES;                        // 512 (scan block sums)
    int* isrc = ibs + 512;                             // E_TOT

    hipMemsetAsync(ideg, 0, (size_t)N_NODES * sizeof(int), stream);

    // CSR build (shared by both layers)
    k_hist<<<(E_TOT + 255) / 256, 256, 0, stream>>>(ei, ideg);
    k_scan1<<<NB1, 256, 0, stream>>>(ideg, ioff, ibs);
    k_scan2<<<1, 512, 0, stream>>>(ibs);
    k_scan3<<<NB1, 256, 0, stream>>>(ioff, ibs, icur);
    k_fill<<<(E_TOT + 255) / 256, 256, 0, stream>>>(ei, icur, isrc);

    // Layer 1
    k_gemm1<<<N_NODES / 32, 256, 0, stream>>>(x, W1, a_src1, a_dst1, xw1, al1, ar1);
    k_aggr1<<<N_NODES, 128, 0, stream>>>(isrc, ioff, ideg, al1, ar1, xw1, b1, out1);

    // Layer 2
    k_gemm2<<<N_NODES / 16, 256, 0, stream>>>(out1, W2, a_src2, a_dst2, xw2, al2, ar2);
    k_aggr2<<<N_NODES / 16, 256, 0, stream>>>(isrc, ioff, ideg, al2, ar2, xw2, b2, out);
}

// Round 4
// 519.142 us; speedup vs baseline: 3.2769x; 1.1001x over previous
//
#include <hip/hip_runtime.h>
#include <hip/hip_fp16.h>

#define N_NODES 100000
#define N_EDGES 1600000
#define E_TOT   (N_EDGES + N_NODES)   // 1,700,000 incl. self-loops
#define NEG_SLOPE 0.2f
#define NB1 ((N_NODES + 255) / 256)   // 391 scan blocks

// ---------------------------------------------------------------------------
// CSR-by-dst construction: histogram -> 3-kernel exclusive scan -> fill.
// ---------------------------------------------------------------------------
__global__ __launch_bounds__(256)
void k_hist(const int* __restrict__ ei, int* __restrict__ deg) {
    const int e = blockIdx.x * blockDim.x + threadIdx.x;
    if (e >= E_TOT) return;
    const int d = (e < N_EDGES) ? ei[N_EDGES + e] : e - N_EDGES;
    atomicAdd(&deg[d], 1);
}

__global__ __launch_bounds__(256)
void k_scan1(const int* __restrict__ deg, int* __restrict__ part, int* __restrict__ bsums) {
    __shared__ int buf[256];
    const int t = threadIdx.x;
    const int i = blockIdx.x * 256 + t;
    int v = (i < N_NODES) ? deg[i] : 0;
    buf[t] = v;
    __syncthreads();
    for (int off = 1; off < 256; off <<= 1) {
        int add = (t >= off) ? buf[t - off] : 0;
        __syncthreads();
        buf[t] += add;
        __syncthreads();
    }
    if (i < N_NODES) part[i] = buf[t] - v;   // exclusive within block
    if (t == 255) bsums[blockIdx.x] = buf[255];
}

__global__ __launch_bounds__(512)
void k_scan2(int* __restrict__ bsums) {
    __shared__ int buf[512];
    const int t = threadIdx.x;
    int v = (t < NB1) ? bsums[t] : 0;
    buf[t] = v;
    __syncthreads();
    for (int off = 1; off < 512; off <<= 1) {
        int add = (t >= off) ? buf[t - off] : 0;
        __syncthreads();
        buf[t] += add;
        __syncthreads();
    }
    if (t < NB1) bsums[t] = buf[t] - v;      // exclusive block offsets
}

__global__ __launch_bounds__(256)
void k_scan3(int* __restrict__ offs, const int* __restrict__ bsums, int* __restrict__ cur) {
    const int i = blockIdx.x * blockDim.x + threadIdx.x;
    if (i >= N_NODES) return;
    const int o = offs[i] + bsums[i >> 8];
    offs[i] = o;
    cur[i] = o;
}

__global__ __launch_bounds__(256)
void k_fill(const int* __restrict__ ei, int* __restrict__ cur, int* __restrict__ ssrc) {
    const int e = blockIdx.x * blockDim.x + threadIdx.x;
    if (e >= E_TOT) return;
    int s, d;
    if (e < N_EDGES) { s = ei[e]; d = ei[N_EDGES + e]; }
    else             { s = d = e - N_EDGES; }
    const int pos = atomicAdd(&cur[d], 1);
    ssrc[pos] = s;
}

// ---------------------------------------------------------------------------
// Layer 1 GEMM, register-tiled: 256 threads, 32 nodes/block, 4x4 tile/thread.
// fp32 math throughout; xw1 written as fp16 (halves the aggr1 gather bytes;
// attention dots al1/ar1 stay fp32 from the fp32 accumulators).
// ---------------------------------------------------------------------------
__global__ __launch_bounds__(256)
void k_gemm1(const float* __restrict__ x, const float* __restrict__ W1,
             const float* __restrict__ a_src1, const float* __restrict__ a_dst1,
             __half* __restrict__ xw1h, float* __restrict__ al1, float* __restrict__ ar1) {
    const int t = threadIdx.x;
    const int n0 = blockIdx.x * 32;
    __shared__ float sx[32][128];   // 16 KB
    __shared__ float sW[32][128];   // 16 KB (one 32-row k-tile of W1)

    {   // stage x tile: 1024 float4s, coalesced
        const float4* xg = (const float4*)(x + (size_t)n0 * 128);
#pragma unroll
        for (int i = 0; i < 4; ++i) {
            const int f = t + i * 256;
            ((float4*)sx)[f] = xg[f];
        }
    }

    const int tj = t & 31;          // column group: cols 4*tj .. 4*tj+3
    const int tn = (t >> 5) * 4;    // node group:   nodes tn .. tn+3
    float4 acc[4] = {{0,0,0,0},{0,0,0,0},{0,0,0,0},{0,0,0,0}};

    for (int kt = 0; kt < 128; kt += 32) {
        __syncthreads();            // sx ready (first iter) / sW drained (later)
        const float4* wg = (const float4*)(W1 + (size_t)kt * 128);
#pragma unroll
        for (int i = 0; i < 4; ++i) {
            const int f = t + i * 256;
            ((float4*)sW)[f] = wg[f];
        }
        __syncthreads();
        for (int k = 0; k < 32; k += 4) {
            float4 xv[4];
#pragma unroll
            for (int i = 0; i < 4; ++i)
                xv[i] = *(const float4*)&sx[tn + i][kt + k];   // broadcast reads
#pragma unroll
            for (int kk = 0; kk < 4; ++kk) {
                const float4 wv = *(const float4*)&sW[k + kk][tj * 4];
#pragma unroll
                for (int i = 0; i < 4; ++i) {
                    const float xs = ((const float*)&xv[i])[kk];
                    acc[i].x = fmaf(xs, wv.x, acc[i].x);
                    acc[i].y = fmaf(xs, wv.y, acc[i].y);
                    acc[i].z = fmaf(xs, wv.z, acc[i].z);
                    acc[i].w = fmaf(xs, wv.w, acc[i].w);
                }
            }
        }
    }

    // write xw1 as fp16 (4 halves = 8B store, aligned)
#pragma unroll
    for (int i = 0; i < 4; ++i) {
        __half hp[4];
        hp[0] = __float2half(acc[i].x);
        hp[1] = __float2half(acc[i].y);
        hp[2] = __float2half(acc[i].z);
        hp[3] = __float2half(acc[i].w);
        *(uint2*)&xw1h[(size_t)(n0 + tn + i) * 128 + tj * 4] = *(uint2*)hp;
    }

    // fused attention dots (fp32): head h = tj>>3
    const float4 asv = ((const float4*)a_src1)[tj];
    const float4 adv = ((const float4*)a_dst1)[tj];
#pragma unroll
    for (int i = 0; i < 4; ++i) {
        float ps = acc[i].x * asv.x + acc[i].y * asv.y + acc[i].z * asv.z + acc[i].w * asv.w;
        float pd = acc[i].x * adv.x + acc[i].y * adv.y + acc[i].z * adv.z + acc[i].w * adv.w;
#pragma unroll
        for (int o = 1; o < 8; o <<= 1) { ps += __shfl_xor(ps, o, 64); pd += __shfl_xor(pd, o, 64); }
        if ((tj & 7) == 0) {
            const int h = tj >> 3;
            al1[(size_t)(n0 + tn + i) * 4 + h] = ps;
            ar1[(size_t)(n0 + tn + i) * 4 + h] = pd;
        }
    }
}

// ---------------------------------------------------------------------------
// Layer 1 pull-aggregation: one block (128 thr) per dst node. fp16 gather,
// fp32 accumulate. 8-deep explicit load batching for latency cover.
// ---------------------------------------------------------------------------
__global__ __launch_bounds__(128)
void k_aggr1(const int* __restrict__ ssrc, const int* __restrict__ offs,
             const int* __restrict__ deg, const float* __restrict__ al1,
             const float* __restrict__ ar1, const __half* __restrict__ xw1h,
             const float* __restrict__ b1, float* __restrict__ out1) {
    const int d = blockIdx.x;
    const int j = threadIdx.x;               // 0..127
    const int h = j >> 5;
    const int beg = offs[d];
    const int n = deg[d];
    __shared__ float w_s[128];               // 32 edges x 4 heads
    __shared__ int s_s[32];
    const float arh = ar1[d * 4 + (j & 3)];  // phase-A role head = j&3
    float acc = 0.f, dnm = 0.f;

    for (int base = 0; base < n; base += 32) {
        const int m = min(32, n - base);
        const int eL = j >> 2, hh = j & 3;
        __syncthreads();                     // protect w_s/s_s reuse
        if (eL < m) {
            const int s = ssrc[beg + base + eL];
            if (hh == 0) s_s[eL] = s;
            float v = al1[s * 4 + hh] + arh;
            v = v > 0.f ? v : NEG_SLOPE * v;
            w_s[eL * 4 + hh] = __expf(v);
        }
        __syncthreads();
        int e = 0;
        for (; e + 8 <= m; e += 8) {
            int   ss[8]; float ww[8]; float vv[8];
#pragma unroll
            for (int u = 0; u < 8; ++u) { ss[u] = s_s[e + u]; ww[u] = w_s[(e + u) * 4 + h]; }
#pragma unroll
            for (int u = 0; u < 8; ++u) vv[u] = __half2float(xw1h[(size_t)ss[u] * 128 + j]);
#pragma unroll
            for (int u = 0; u < 8; ++u) { acc = fmaf(ww[u], vv[u], acc); dnm += ww[u]; }
        }
        for (; e < m; ++e) {
            const float w = w_s[e * 4 + h];
            const int s = s_s[e];
            acc = fmaf(w, __half2float(xw1h[(size_t)s * 128 + j]), acc);
            dnm += w;
        }
    }
    const float hv = acc / dnm + b1[j];
    out1[d * 128 + j] = hv > 0.f ? hv : 0.f;  // fused bias + ReLU
}

// ---------------------------------------------------------------------------
// Layer 2 GEMM: 16 nodes/block, 256 threads. xw2 stored fp16, al2/ar2 fp32.
// ---------------------------------------------------------------------------
__global__ __launch_bounds__(256)
void k_gemm2(const float* __restrict__ out1, const float* __restrict__ W2,
             const float* __restrict__ a_src2, const float* __restrict__ a_dst2,
             __half* __restrict__ xw2h, float* __restrict__ al2, float* __restrict__ ar2) {
    const int t = threadIdx.x;
    const int node0 = blockIdx.x * 16;
    __shared__ float sW[128 * 16];
    __shared__ float sh[16][129];            // +1 pad: kills 4-way bank conflict
    for (int i = t; i < 2048; i += 256) sW[i] = W2[i];
    for (int i = t; i < 2048; i += 256) {
        const int nn = i >> 7, kk = i & 127;
        sh[nn][kk] = out1[(node0 + nn) * 128 + kk];   // bias+relu already applied
    }
    __syncthreads();
    const int nn = t >> 4;                   // 0..15
    const int j = t & 15;
    float acc = 0.f;
#pragma unroll 8
    for (int k = 0; k < 128; ++k)
        acc = fmaf(sh[nn][k], sW[k * 16 + j], acc);
    xw2h[(node0 + nn) * 16 + j] = __float2half(acc);

    float ps = acc * a_src2[j];
    float pd = acc * a_dst2[j];
#pragma unroll
    for (int o = 8; o; o >>= 1) { ps += __shfl_xor(ps, o, 64); pd += __shfl_xor(pd, o, 64); }
    if (j == 0) { al2[node0 + nn] = ps; ar2[node0 + nn] = pd; }
}

// ---------------------------------------------------------------------------
// Layer 2 pull-aggregation: one WAVE per node; lane = eL*16+j (4 edges x 16
// features in flight), x2 unroll = 8 edges outstanding. Cross-group shuffle
// reduction at the end. Fused +b2, writes d_out once.
// ---------------------------------------------------------------------------
__global__ __launch_bounds__(256)
void k_aggr2(const int* __restrict__ ssrc, const int* __restrict__ offs,
             const int* __restrict__ deg, const float* __restrict__ al2,
             const float* __restrict__ ar2, const __half* __restrict__ xw2h,
             const float* __restrict__ b2, float* __restrict__ out) {
    const int lane = threadIdx.x & 63;
    const int node = blockIdx.x * 4 + (threadIdx.x >> 6);
    const int j = lane & 15;
    const int eL = lane >> 4;                // 0..3
    const int beg = offs[node];
    const int n = deg[node];
    const float ard = ar2[node];
    float acc = 0.f, dnm = 0.f;
    int base = 0;
    for (; base + 8 <= n; base += 8) {
#pragma unroll
        for (int u = 0; u < 2; ++u) {
            const int s = ssrc[beg + base + u * 4 + eL];
            float v = al2[s] + ard;
            v = v > 0.f ? v : NEG_SLOPE * v;
            const float w = __expf(v);
            acc = fmaf(w, __half2float(xw2h[(size_t)s * 16 + j]), acc);
            dnm += w;
        }
    }
    for (; base < n; base += 4) {
        const int e = base + eL;
        if (e < n) {
            const int s = ssrc[beg + e];
            float v = al2[s] + ard;
            v = v > 0.f ? v : NEG_SLOPE * v;
            const float w = __expf(v);
            acc = fmaf(w, __half2float(xw2h[(size_t)s * 16 + j]), acc);
            dnm += w;
        }
    }
    // reduce across the 4 edge-groups (lanes with same j)
    acc += __shfl_xor(acc, 16, 64); acc += __shfl_xor(acc, 32, 64);
    dnm += __shfl_xor(dnm, 16, 64); dnm += __shfl_xor(dnm, 32, 64);
    if (eL == 0)
        out[(size_t)node * 16 + j] = acc / dnm + b2[j];
}

extern "C" void kernel_launch(void* const* d_in, const int* in_sizes, int n_in,
                              void* d_out, int out_size, void* d_ws, size_t ws_size,
                              hipStream_t stream) {
    const float* x      = (const float*)d_in[0];
    const int*   ei     = (const int*)d_in[1];
    const float* W1     = (const float*)d_in[2];
    const float* a_src1 = (const float*)d_in[3];
    const float* a_dst1 = (const float*)d_in[4];
    const float* b1     = (const float*)d_in[5];
    const float* W2     = (const float*)d_in[6];
    const float* a_src2 = (const float*)d_in[7];
    const float* a_dst2 = (const float*)d_in[8];
    const float* b2     = (const float*)d_in[9];
    float* out = (float*)d_out;

    // Workspace (byte-addressed). xw1h region is dead after k_aggr1 and is
    // reused for xw2h/al2/ar2 (written by k_gemm2, which only reads out1).
    char* wsb = (char*)d_ws;
    __half* xw1h = (__half*)wsb;                                  // N*128 half (25.6 MB)
    __half* xw2h = (__half*)wsb;                                  // N*16 half (alias)
    float*  al2  = (float*)(wsb + (size_t)N_NODES * 16 * 2);      // N fp32 (alias, past xw2h)
    float*  ar2  = al2 + N_NODES;                                 // N fp32 (alias)
    float*  out1 = (float*)(wsb + (size_t)N_NODES * 128 * 2);     // N*128 fp32
    float*  al1  = out1 + (size_t)N_NODES * 128;                  // N*4
    float*  ar1  = al1 + (size_t)N_NODES * 4;                     // N*4
    int* ideg = (int*)(ar1 + (size_t)N_NODES * 4);                // N
    int* ioff = ideg + N_NODES;                                   // N
    int* icur = ioff + N_NODES;                                   // N
    int* ibs  = icur + N_NODES;                                   // 512
    int* isrc = ibs + 512;                                        // E_TOT

    hipMemsetAsync(ideg, 0, (size_t)N_NODES * sizeof(int), stream);

    // CSR build (shared by both layers)
    k_hist<<<(E_TOT + 255) / 256, 256, 0, stream>>>(ei, ideg);
    k_scan1<<<NB1, 256, 0, stream>>>(ideg, ioff, ibs);
    k_scan2<<<1, 512, 0, stream>>>(ibs);
    k_scan3<<<NB1, 256, 0, stream>>>(ioff, ibs, icur);
    k_fill<<<(E_TOT + 255) / 256, 256, 0, stream>>>(ei, icur, isrc);

    // Layer 1
    k_gemm1<<<N_NODES / 32, 256, 0, stream>>>(x, W1, a_src1, a_dst1, xw1h, al1, ar1);
    k_aggr1<<<N_NODES, 128, 0, stream>>>(isrc, ioff, ideg, al1, ar1, xw1h, b1, out1);

    // Layer 2
    k_gemm2<<<N_NODES / 16, 256, 0, stream>>>(out1, W2, a_src2, a_dst2, xw2h, al2, ar2);
    k_aggr2<<<N_NODES / 4, 256, 0, stream>>>(isrc, ioff, ideg, al2, ar2, xw2h, b2, out);
}

// Round 5
// 500.124 us; speedup vs baseline: 3.4015x; 1.0380x over previous
//
#include <hip/hip_runtime.h>
#include <hip/hip_fp16.h>

#define N_NODES 100000
#define N_EDGES 1600000
#define E_TOT   (N_EDGES + N_NODES)   // 1,700,000 incl. self-loops
#define NEG_SLOPE 0.2f
#define NB1 ((N_NODES + 255) / 256)   // 391 scan blocks
#define NBUCK 98                      // ceil(N_NODES / 1024) coarse dst-buckets
#define PART_EPB 4096                 // edges per k_part block

// ---------------------------------------------------------------------------
// CSR-by-dst construction: histogram -> scan -> bucket partition -> local fill.
// The partition step exists purely to fix HBM write amplification: a direct
// atomic fill scatters 4B stores over 6.8MB -> 108MB of partial-line
// writebacks (R4 counters). Bucket-grouping makes the final fill's writes
// L2-local so lines fill completely (~7MB writeback).
// ---------------------------------------------------------------------------
__global__ __launch_bounds__(256)
void k_hist(const int* __restrict__ ei, int* __restrict__ deg) {
    const int e = blockIdx.x * blockDim.x + threadIdx.x;
    if (e >= E_TOT) return;
    const int d = (e < N_EDGES) ? ei[N_EDGES + e] : e - N_EDGES;
    atomicAdd(&deg[d], 1);
}

__global__ __launch_bounds__(256)
void k_scan1(const int* __restrict__ deg, int* __restrict__ part, int* __restrict__ bsums) {
    __shared__ int buf[256];
    const int t = threadIdx.x;
    const int i = blockIdx.x * 256 + t;
    int v = (i < N_NODES) ? deg[i] : 0;
    buf[t] = v;
    __syncthreads();
    for (int off = 1; off < 256; off <<= 1) {
        int add = (t >= off) ? buf[t - off] : 0;
        __syncthreads();
        buf[t] += add;
        __syncthreads();
    }
    if (i < N_NODES) part[i] = buf[t] - v;   // exclusive within block
    if (t == 255) bsums[blockIdx.x] = buf[255];
}

__global__ __launch_bounds__(512)
void k_scan2(int* __restrict__ bsums) {
    __shared__ int buf[512];
    const int t = threadIdx.x;
    int v = (t < NB1) ? bsums[t] : 0;
    buf[t] = v;
    __syncthreads();
    for (int off = 1; off < 512; off <<= 1) {
        int add = (t >= off) ? buf[t - off] : 0;
        __syncthreads();
        buf[t] += add;
        __syncthreads();
    }
    if (t < NB1) bsums[t] = buf[t] - v;      // exclusive block offsets
}

__global__ __launch_bounds__(256)
void k_scan3(int* __restrict__ offs, const int* __restrict__ bsums,
             int* __restrict__ cur, int* __restrict__ bcur) {
    const int i = blockIdx.x * blockDim.x + threadIdx.x;
    if (i >= N_NODES) return;
    const int o = offs[i] + bsums[i >> 8];
    offs[i] = o;
    cur[i] = o;
    if ((i & 1023) == 0) bcur[i >> 10] = o;  // coarse-bucket write cursors
}

// Partition edges into 98 coarse buckets (dst>>10). Per-block LDS histogram,
// one global atomic per (block,bucket) to reserve a contiguous range, then
// grouped pair writes (~42 edges = 336B contiguous per bucket per block).
__global__ __launch_bounds__(256)
void k_part(const int* __restrict__ ei, int* __restrict__ bcur, int2* __restrict__ pairs) {
    const int t = threadIdx.x;
    const int base = blockIdx.x * PART_EPB;
    __shared__ int lcnt[128];
    __shared__ int lbase[128];
    if (t < 128) lcnt[t] = 0;
    __syncthreads();
    int sr[16], dr[16];
#pragma unroll
    for (int u = 0; u < 16; ++u) {
        const int e = base + u * 256 + t;    // coalesced
        if (e < E_TOT) {
            int s, d;
            if (e < N_EDGES) { s = ei[e]; d = ei[N_EDGES + e]; }
            else             { s = d = e - N_EDGES; }
            sr[u] = s; dr[u] = d;
            atomicAdd(&lcnt[d >> 10], 1);
        } else dr[u] = -1;
    }
    __syncthreads();
    if (t < 128) {
        const int c = lcnt[t];
        lbase[t] = (c > 0) ? atomicAdd(&bcur[t], c) : 0;
        lcnt[t] = 0;                         // reuse as local cursor
    }
    __syncthreads();
#pragma unroll
    for (int u = 0; u < 16; ++u) {
        if (dr[u] >= 0) {
            const int bk = dr[u] >> 10;
            const int r = atomicAdd(&lcnt[bk], 1);
            pairs[lbase[bk] + r] = make_int2(sr[u], dr[u]);
        }
    }
}

// Fine fill from bucket-grouped pairs. Inverse-round-robin swizzle keeps each
// contiguous edge chunk (-> contiguous ssrc region) on one XCD so dirty lines
// fill completely in that XCD's L2 before writeback.
__global__ __launch_bounds__(256)
void k_fill2(const int2* __restrict__ pairs, int* __restrict__ cur, int* __restrict__ ssrc) {
    const int nb8 = gridDim.x >> 3;          // grid is padded to a multiple of 8
    const int vb = (blockIdx.x & 7) * nb8 + (blockIdx.x >> 3);
    const int e = vb * 256 + (int)threadIdx.x;
    if (e >= E_TOT) return;
    const int2 p = pairs[e];
    const int pos = atomicAdd(&cur[p.y], 1);
    ssrc[pos] = p.x;
}

// ---------------------------------------------------------------------------
// Layer 1 GEMM, register-tiled: 256 threads, 32 nodes/block, 4x4 tile/thread.
// fp32 math; xw1 stored fp16 (halves aggr1 gather bytes; al1/ar1 stay fp32).
// ---------------------------------------------------------------------------
__global__ __launch_bounds__(256)
void k_gemm1(const float* __restrict__ x, const float* __restrict__ W1,
             const float* __restrict__ a_src1, const float* __restrict__ a_dst1,
             __half* __restrict__ xw1h, float* __restrict__ al1, float* __restrict__ ar1) {
    const int t = threadIdx.x;
    const int n0 = blockIdx.x * 32;
    __shared__ float sx[32][128];   // 16 KB
    __shared__ float sW[32][128];   // 16 KB (one 32-row k-tile of W1)

    {   // stage x tile: 1024 float4s, coalesced
        const float4* xg = (const float4*)(x + (size_t)n0 * 128);
#pragma unroll
        for (int i = 0; i < 4; ++i) {
            const int f = t + i * 256;
            ((float4*)sx)[f] = xg[f];
        }
    }

    const int tj = t & 31;          // column group: cols 4*tj .. 4*tj+3
    const int tn = (t >> 5) * 4;    // node group:   nodes tn .. tn+3
    float4 acc[4] = {{0,0,0,0},{0,0,0,0},{0,0,0,0},{0,0,0,0}};

    for (int kt = 0; kt < 128; kt += 32) {
        __syncthreads();            // sx ready (first iter) / sW drained (later)
        const float4* wg = (const float4*)(W1 + (size_t)kt * 128);
#pragma unroll
        for (int i = 0; i < 4; ++i) {
            const int f = t + i * 256;
            ((float4*)sW)[f] = wg[f];
        }
        __syncthreads();
        for (int k = 0; k < 32; k += 4) {
            float4 xv[4];
#pragma unroll
            for (int i = 0; i < 4; ++i)
                xv[i] = *(const float4*)&sx[tn + i][kt + k];   // broadcast reads
#pragma unroll
            for (int kk = 0; kk < 4; ++kk) {
                const float4 wv = *(const float4*)&sW[k + kk][tj * 4];
#pragma unroll
                for (int i = 0; i < 4; ++i) {
                    const float xs = ((const float*)&xv[i])[kk];
                    acc[i].x = fmaf(xs, wv.x, acc[i].x);
                    acc[i].y = fmaf(xs, wv.y, acc[i].y);
                    acc[i].z = fmaf(xs, wv.z, acc[i].z);
                    acc[i].w = fmaf(xs, wv.w, acc[i].w);
                }
            }
        }
    }

    // write xw1 as fp16 (4 halves = 8B store, aligned)
#pragma unroll
    for (int i = 0; i < 4; ++i) {
        __half hp[4];
        hp[0] = __float2half(acc[i].x);
        hp[1] = __float2half(acc[i].y);
        hp[2] = __float2half(acc[i].z);
        hp[3] = __float2half(acc[i].w);
        *(uint2*)&xw1h[(size_t)(n0 + tn + i) * 128 + tj * 4] = *(uint2*)hp;
    }

    // fused attention dots (fp32): head h = tj>>3
    const float4 asv = ((const float4*)a_src1)[tj];
    const float4 adv = ((const float4*)a_dst1)[tj];
#pragma unroll
    for (int i = 0; i < 4; ++i) {
        float ps = acc[i].x * asv.x + acc[i].y * asv.y + acc[i].z * asv.z + acc[i].w * asv.w;
        float pd = acc[i].x * adv.x + acc[i].y * adv.y + acc[i].z * adv.z + acc[i].w * adv.w;
#pragma unroll
        for (int o = 1; o < 8; o <<= 1) { ps += __shfl_xor(ps, o, 64); pd += __shfl_xor(pd, o, 64); }
        if ((tj & 7) == 0) {
            const int h = tj >> 3;
            al1[(size_t)(n0 + tn + i) * 4 + h] = ps;
            ar1[(size_t)(n0 + tn + i) * 4 + h] = pd;
        }
    }
}

// ---------------------------------------------------------------------------
// Layer 1 pull-aggregation: one block (128 thr) per dst node. fp16 gather,
// fp32 accumulate. 8-deep explicit load batching for latency cover.
// ---------------------------------------------------------------------------
__global__ __launch_bounds__(128)
void k_aggr1(const int* __restrict__ ssrc, const int* __restrict__ offs,
             const int* __restrict__ deg, const float* __restrict__ al1,
             const float* __restrict__ ar1, const __half* __restrict__ xw1h,
             const float* __restrict__ b1, float* __restrict__ out1) {
    const int d = blockIdx.x;
    const int j = threadIdx.x;               // 0..127
    const int h = j >> 5;
    const int beg = offs[d];
    const int n = deg[d];
    __shared__ float w_s[128];               // 32 edges x 4 heads
    __shared__ int s_s[32];
    const float arh = ar1[d * 4 + (j & 3)];  // phase-A role head = j&3
    float acc = 0.f, dnm = 0.f;

    for (int base = 0; base < n; base += 32) {
        const int m = min(32, n - base);
        const int eL = j >> 2, hh = j & 3;
        __syncthreads();                     // protect w_s/s_s reuse
        if (eL < m) {
            const int s = ssrc[beg + base + eL];
            if (hh == 0) s_s[eL] = s;
            float v = al1[s * 4 + hh] + arh;
            v = v > 0.f ? v : NEG_SLOPE * v;
            w_s[eL * 4 + hh] = __expf(v);
        }
        __syncthreads();
        int e = 0;
        for (; e + 8 <= m; e += 8) {
            int   ss[8]; float ww[8]; float vv[8];
#pragma unroll
            for (int u = 0; u < 8; ++u) { ss[u] = s_s[e + u]; ww[u] = w_s[(e + u) * 4 + h]; }
#pragma unroll
            for (int u = 0; u < 8; ++u) vv[u] = __half2float(xw1h[(size_t)ss[u] * 128 + j]);
#pragma unroll
            for (int u = 0; u < 8; ++u) { acc = fmaf(ww[u], vv[u], acc); dnm += ww[u]; }
        }
        for (; e < m; ++e) {
            const float w = w_s[e * 4 + h];
            const int s = s_s[e];
            acc = fmaf(w, __half2float(xw1h[(size_t)s * 128 + j]), acc);
            dnm += w;
        }
    }
    const float hv = acc / dnm + b1[j];
    out1[d * 128 + j] = hv > 0.f ? hv : 0.f;  // fused bias + ReLU
}

// ---------------------------------------------------------------------------
// Layer 2 GEMM: 16 nodes/block, 256 threads. xw2 stored fp16, al2/ar2 fp32.
// ---------------------------------------------------------------------------
__global__ __launch_bounds__(256)
void k_gemm2(const float* __restrict__ out1, const float* __restrict__ W2,
             const float* __restrict__ a_src2, const float* __restrict__ a_dst2,
             __half* __restrict__ xw2h, float* __restrict__ al2, float* __restrict__ ar2) {
    const int t = threadIdx.x;
    const int node0 = blockIdx.x * 16;
    __shared__ float sW[128 * 16];
    __shared__ float sh[16][129];            // +1 pad: kills 4-way bank conflict
    for (int i = t; i < 2048; i += 256) sW[i] = W2[i];
    for (int i = t; i < 2048; i += 256) {
        const int nn = i >> 7, kk = i & 127;
        sh[nn][kk] = out1[(node0 + nn) * 128 + kk];   // bias+relu already applied
    }
    __syncthreads();
    const int nn = t >> 4;                   // 0..15
    const int j = t & 15;
    float acc = 0.f;
#pragma unroll 8
    for (int k = 0; k < 128; ++k)
        acc = fmaf(sh[nn][k], sW[k * 16 + j], acc);
    xw2h[(node0 + nn) * 16 + j] = __float2half(acc);

    float ps = acc * a_src2[j];
    float pd = acc * a_dst2[j];
#pragma unroll
    for (int o = 8; o; o >>= 1) { ps += __shfl_xor(ps, o, 64); pd += __shfl_xor(pd, o, 64); }
    if (j == 0) { al2[node0 + nn] = ps; ar2[node0 + nn] = pd; }
}

// ---------------------------------------------------------------------------
// Layer 2 pull-aggregation: one WAVE per node; lane = eL*16+j.
// ---------------------------------------------------------------------------
__global__ __launch_bounds__(256)
void k_aggr2(const int* __restrict__ ssrc, const int* __restrict__ offs,
             const int* __restrict__ deg, const float* __restrict__ al2,
             const float* __restrict__ ar2, const __half* __restrict__ xw2h,
             const float* __restrict__ b2, float* __restrict__ out) {
    const int lane = threadIdx.x & 63;
    const int node = blockIdx.x * 4 + (threadIdx.x >> 6);
    const int j = lane & 15;
    const int eL = lane >> 4;                // 0..3
    const int beg = offs[node];
    const int n = deg[node];
    const float ard = ar2[node];
    float acc = 0.f, dnm = 0.f;
    int base = 0;
    for (; base + 8 <= n; base += 8) {
#pragma unroll
        for (int u = 0; u < 2; ++u) {
            const int s = ssrc[beg + base + u * 4 + eL];
            float v = al2[s] + ard;
            v = v > 0.f ? v : NEG_SLOPE * v;
            const float w = __expf(v);
            acc = fmaf(w, __half2float(xw2h[(size_t)s * 16 + j]), acc);
            dnm += w;
        }
    }
    for (; base < n; base += 4) {
        const int e = base + eL;
        if (e < n) {
            const int s = ssrc[beg + e];
            float v = al2[s] + ard;
            v = v > 0.f ? v : NEG_SLOPE * v;
            const float w = __expf(v);
            acc = fmaf(w, __half2float(xw2h[(size_t)s * 16 + j]), acc);
            dnm += w;
        }
    }
    acc += __shfl_xor(acc, 16, 64); acc += __shfl_xor(acc, 32, 64);
    dnm += __shfl_xor(dnm, 16, 64); dnm += __shfl_xor(dnm, 32, 64);
    if (eL == 0)
        out[(size_t)node * 16 + j] = acc / dnm + b2[j];
}

extern "C" void kernel_launch(void* const* d_in, const int* in_sizes, int n_in,
                              void* d_out, int out_size, void* d_ws, size_t ws_size,
                              hipStream_t stream) {
    const float* x      = (const float*)d_in[0];
    const int*   ei     = (const int*)d_in[1];
    const float* W1     = (const float*)d_in[2];
    const float* a_src1 = (const float*)d_in[3];
    const float* a_dst1 = (const float*)d_in[4];
    const float* b1     = (const float*)d_in[5];
    const float* W2     = (const float*)d_in[6];
    const float* a_src2 = (const float*)d_in[7];
    const float* a_dst2 = (const float*)d_in[8];
    const float* b2     = (const float*)d_in[9];
    float* out = (float*)d_out;

    // Workspace (byte-addressed). Aliases:
    //  - pairs (13.6MB) sits in out1's region: consumed by k_fill2 before
    //    k_aggr1 writes out1.
    //  - xw2h/al2/ar2 sit in xw1h's region: written by k_gemm2 after k_aggr1
    //    is done with xw1h.
    char* wsb = (char*)d_ws;
    __half* xw1h = (__half*)wsb;                                  // N*128 half (25.6 MB)
    __half* xw2h = (__half*)wsb;                                  // N*16 half (alias)
    float*  al2  = (float*)(wsb + (size_t)N_NODES * 16 * 2);      // N fp32 (alias)
    float*  ar2  = al2 + N_NODES;                                 // N fp32 (alias)
    float*  out1 = (float*)(wsb + (size_t)N_NODES * 128 * 2);     // N*128 fp32 (51.2 MB)
    int2*   pairs = (int2*)out1;                                  // E_TOT int2 (alias)
    float*  al1  = out1 + (size_t)N_NODES * 128;                  // N*4
    float*  ar1  = al1 + (size_t)N_NODES * 4;                     // N*4
    int* ideg = (int*)(ar1 + (size_t)N_NODES * 4);                // N
    int* ioff = ideg + N_NODES;                                   // N
    int* icur = ioff + N_NODES;                                   // N
    int* ibs  = icur + N_NODES;                                   // 512
    int* ibcur = ibs + 512;                                       // 128
    int* isrc = ibcur + 128;                                      // E_TOT

    hipMemsetAsync(ideg, 0, (size_t)N_NODES * sizeof(int), stream);

    // CSR build (shared by both layers)
    k_hist<<<(E_TOT + 255) / 256, 256, 0, stream>>>(ei, ideg);
    k_scan1<<<NB1, 256, 0, stream>>>(ideg, ioff, ibs);
    k_scan2<<<1, 512, 0, stream>>>(ibs);
    k_scan3<<<NB1, 256, 0, stream>>>(ioff, ibs, icur, ibcur);
    k_part<<<(E_TOT + PART_EPB - 1) / PART_EPB, 256, 0, stream>>>(ei, ibcur, pairs);
    {   // grid padded to a multiple of 8 for the XCD swizzle
        int g = (E_TOT + 255) / 256;
        g = (g + 7) & ~7;
        k_fill2<<<g, 256, 0, stream>>>(pairs, icur, isrc);
    }

    // Layer 1
    k_gemm1<<<N_NODES / 32, 256, 0, stream>>>(x, W1, a_src1, a_dst1, xw1h, al1, ar1);
    k_aggr1<<<N_NODES, 128, 0, stream>>>(isrc, ioff, ideg, al1, ar1, xw1h, b1, out1);

    // Layer 2
    k_gemm2<<<N_NODES / 16, 256, 0, stream>>>(out1, W2, a_src2, a_dst2, xw2h, al2, ar2);
    k_aggr2<<<N_NODES / 4, 256, 0, stream>>>(isrc, ioff, ideg, al2, ar2, xw2h, b2, out);
}

// Round 6
// 498.363 us; speedup vs baseline: 3.4135x; 1.0035x over previous
//
#include <hip/hip_runtime.h>
#include <hip/hip_fp16.h>

#define N_NODES 100000
#define N_EDGES 1600000
#define E_TOT   (N_EDGES + N_NODES)   // 1,700,000 incl. self-loops
#define NEG_SLOPE 0.2f
#define NB1 ((N_NODES + 255) / 256)   // 391 scan blocks
#define PART_EPB 4096                 // edges per k_part block

// ---------------------------------------------------------------------------
// CSR-by-dst construction: histogram -> scan -> bucket partition -> local fill.
// Partition fixes HBM write amplification (R4: direct fill = 108MB writeback
// for a 6.8MB payload; bucketed fill ~ 7MB).
// ---------------------------------------------------------------------------
__global__ __launch_bounds__(256)
void k_hist(const int* __restrict__ ei, int* __restrict__ deg) {
    const int e = blockIdx.x * blockDim.x + threadIdx.x;
    if (e >= E_TOT) return;
    const int d = (e < N_EDGES) ? ei[N_EDGES + e] : e - N_EDGES;
    atomicAdd(&deg[d], 1);
}

__global__ __launch_bounds__(256)
void k_scan1(const int* __restrict__ deg, int* __restrict__ part, int* __restrict__ bsums) {
    __shared__ int buf[256];
    const int t = threadIdx.x;
    const int i = blockIdx.x * 256 + t;
    int v = (i < N_NODES) ? deg[i] : 0;
    buf[t] = v;
    __syncthreads();
    for (int off = 1; off < 256; off <<= 1) {
        int add = (t >= off) ? buf[t - off] : 0;
        __syncthreads();
        buf[t] += add;
        __syncthreads();
    }
    if (i < N_NODES) part[i] = buf[t] - v;   // exclusive within block
    if (t == 255) bsums[blockIdx.x] = buf[255];
}

__global__ __launch_bounds__(512)
void k_scan2(int* __restrict__ bsums) {
    __shared__ int buf[512];
    const int t = threadIdx.x;
    int v = (t < NB1) ? bsums[t] : 0;
    buf[t] = v;
    __syncthreads();
    for (int off = 1; off < 512; off <<= 1) {
        int add = (t >= off) ? buf[t - off] : 0;
        __syncthreads();
        buf[t] += add;
        __syncthreads();
    }
    if (t < NB1) bsums[t] = buf[t] - v;      // exclusive block offsets
}

__global__ __launch_bounds__(256)
void k_scan3(int* __restrict__ offs, const int* __restrict__ bsums,
             int* __restrict__ cur, int* __restrict__ bcur) {
    const int i = blockIdx.x * blockDim.x + threadIdx.x;
    if (i >= N_NODES) return;
    const int o = offs[i] + bsums[i >> 8];
    offs[i] = o;
    cur[i] = o;
    if ((i & 1023) == 0) bcur[i >> 10] = o;  // coarse-bucket write cursors
}

// Partition edges into 98 coarse buckets (dst>>10).
__global__ __launch_bounds__(256)
void k_part(const int* __restrict__ ei, int* __restrict__ bcur, int2* __restrict__ pairs) {
    const int t = threadIdx.x;
    const int base = blockIdx.x * PART_EPB;
    __shared__ int lcnt[128];
    __shared__ int lbase[128];
    if (t < 128) lcnt[t] = 0;
    __syncthreads();
    int sr[16], dr[16];
#pragma unroll
    for (int u = 0; u < 16; ++u) {
        const int e = base + u * 256 + t;    // coalesced
        if (e < E_TOT) {
            int s, d;
            if (e < N_EDGES) { s = ei[e]; d = ei[N_EDGES + e]; }
            else             { s = d = e - N_EDGES; }
            sr[u] = s; dr[u] = d;
            atomicAdd(&lcnt[d >> 10], 1);
        } else dr[u] = -1;
    }
    __syncthreads();
    if (t < 128) {
        const int c = lcnt[t];
        lbase[t] = (c > 0) ? atomicAdd(&bcur[t], c) : 0;
        lcnt[t] = 0;                         // reuse as local cursor
    }
    __syncthreads();
#pragma unroll
    for (int u = 0; u < 16; ++u) {
        if (dr[u] >= 0) {
            const int bk = dr[u] >> 10;
            const int r = atomicAdd(&lcnt[bk], 1);
            pairs[lbase[bk] + r] = make_int2(sr[u], dr[u]);
        }
    }
}

// Fine fill from bucket-grouped pairs; XCD swizzle keeps writes L2-local.
__global__ __launch_bounds__(256)
void k_fill2(const int2* __restrict__ pairs, int* __restrict__ cur, int* __restrict__ ssrc) {
    const int nb8 = gridDim.x >> 3;          // grid is padded to a multiple of 8
    const int vb = (blockIdx.x & 7) * nb8 + (blockIdx.x >> 3);
    const int e = vb * 256 + (int)threadIdx.x;
    if (e >= E_TOT) return;
    const int2 p = pairs[e];
    const int pos = atomicAdd(&cur[p.y], 1);
    ssrc[pos] = p.x;
}

// ---------------------------------------------------------------------------
// Layer 1 GEMM, register-tiled: 256 threads, 32 nodes/block, 4x4 tile/thread.
// fp32 math; xw1 stored fp16.
// ---------------------------------------------------------------------------
__global__ __launch_bounds__(256)
void k_gemm1(const float* __restrict__ x, const float* __restrict__ W1,
             const float* __restrict__ a_src1, const float* __restrict__ a_dst1,
             __half* __restrict__ xw1h, float* __restrict__ al1, float* __restrict__ ar1) {
    const int t = threadIdx.x;
    const int n0 = blockIdx.x * 32;
    __shared__ float sx[32][128];   // 16 KB
    __shared__ float sW[32][128];   // 16 KB (one 32-row k-tile of W1)

    {   // stage x tile: 1024 float4s, coalesced
        const float4* xg = (const float4*)(x + (size_t)n0 * 128);
#pragma unroll
        for (int i = 0; i < 4; ++i) {
            const int f = t + i * 256;
            ((float4*)sx)[f] = xg[f];
        }
    }

    const int tj = t & 31;          // column group: cols 4*tj .. 4*tj+3
    const int tn = (t >> 5) * 4;    // node group:   nodes tn .. tn+3
    float4 acc[4] = {{0,0,0,0},{0,0,0,0},{0,0,0,0},{0,0,0,0}};

    for (int kt = 0; kt < 128; kt += 32) {
        __syncthreads();
        const float4* wg = (const float4*)(W1 + (size_t)kt * 128);
#pragma unroll
        for (int i = 0; i < 4; ++i) {
            const int f = t + i * 256;
            ((float4*)sW)[f] = wg[f];
        }
        __syncthreads();
        for (int k = 0; k < 32; k += 4) {
            float4 xv[4];
#pragma unroll
            for (int i = 0; i < 4; ++i)
                xv[i] = *(const float4*)&sx[tn + i][kt + k];   // broadcast reads
#pragma unroll
            for (int kk = 0; kk < 4; ++kk) {
                const float4 wv = *(const float4*)&sW[k + kk][tj * 4];
#pragma unroll
                for (int i = 0; i < 4; ++i) {
                    const float xs = ((const float*)&xv[i])[kk];
                    acc[i].x = fmaf(xs, wv.x, acc[i].x);
                    acc[i].y = fmaf(xs, wv.y, acc[i].y);
                    acc[i].z = fmaf(xs, wv.z, acc[i].z);
                    acc[i].w = fmaf(xs, wv.w, acc[i].w);
                }
            }
        }
    }

    // write xw1 as fp16 (4 halves = 8B store, aligned)
#pragma unroll
    for (int i = 0; i < 4; ++i) {
        __half hp[4];
        hp[0] = __float2half(acc[i].x);
        hp[1] = __float2half(acc[i].y);
        hp[2] = __float2half(acc[i].z);
        hp[3] = __float2half(acc[i].w);
        *(uint2*)&xw1h[(size_t)(n0 + tn + i) * 128 + tj * 4] = *(uint2*)hp;
    }

    // fused attention dots (fp32): head h = tj>>3
    const float4 asv = ((const float4*)a_src1)[tj];
    const float4 adv = ((const float4*)a_dst1)[tj];
#pragma unroll
    for (int i = 0; i < 4; ++i) {
        float ps = acc[i].x * asv.x + acc[i].y * asv.y + acc[i].z * asv.z + acc[i].w * asv.w;
        float pd = acc[i].x * adv.x + acc[i].y * adv.y + acc[i].z * adv.z + acc[i].w * adv.w;
#pragma unroll
        for (int o = 1; o < 8; o <<= 1) { ps += __shfl_xor(ps, o, 64); pd += __shfl_xor(pd, o, 64); }
        if ((tj & 7) == 0) {
            const int h = tj >> 3;
            al1[(size_t)(n0 + tn + i) * 4 + h] = ps;
            ar1[(size_t)(n0 + tn + i) * 4 + h] = pd;
        }
    }
}

// ---------------------------------------------------------------------------
// Layer 1 pull-aggregation, vectorized: thread (g,c) = 4 edge-groups x 32
// feature-quads. Each lane gathers uint2 (4 halves, 8B) -> one wave-load
// moves 512B (2 edge rows) vs 128B scalar before. 8 loads in flight/thread.
// Cross-group reduction via LDS; epilogue fuses /denom + b1 + ReLU, writes
// out1 as fp16.
// ---------------------------------------------------------------------------
__global__ __launch_bounds__(128)
void k_aggr1(const int* __restrict__ ssrc, const int* __restrict__ offs,
             const int* __restrict__ deg, const float* __restrict__ al1,
             const float* __restrict__ ar1, const __half* __restrict__ xw1h,
             const float* __restrict__ b1, __half* __restrict__ out1h) {
    const int d = blockIdx.x;
    const int t = threadIdx.x;               // 0..127
    const int g = t >> 5;                    // edge group 0..3
    const int c = t & 31;                    // feature quad: features 4c..4c+3
    const int h = c >> 3;                    // head of this quad
    const int beg = offs[d];
    const int n = deg[d];
    __shared__ float w_s[32][4];
    __shared__ int s_s[32];
    __shared__ float racc[4][128];
    __shared__ float rd[4][4];
    const float arh = ar1[d * 4 + (t & 3)];  // phase-A role head = t&3
    float acc0 = 0.f, acc1 = 0.f, acc2 = 0.f, acc3 = 0.f, dnm = 0.f;

    for (int base = 0; base < n; base += 32) {
        const int m = min(32, n - base);
        __syncthreads();                     // protect w_s/s_s reuse
        const int eL = t >> 2, hh = t & 3;
        if (eL < m) {
            const int s = ssrc[beg + base + eL];
            if (hh == 0) s_s[eL] = s;
            float v = al1[s * 4 + hh] + arh;
            v = v > 0.f ? v : NEG_SLOPE * v;
            w_s[eL][hh] = __expf(v);
        }
        __syncthreads();
        int ss[8]; float ww[8]; uint2 rv[8];
#pragma unroll
        for (int q = 0; q < 8; ++q) {
            const int e = q * 4 + g;
            const bool p = e < m;
            ss[q] = s_s[p ? e : 0];          // safe duplicate (L1-hot) when past tail
            ww[q] = p ? w_s[e][h] : 0.f;
        }
#pragma unroll
        for (int q = 0; q < 8; ++q)
            rv[q] = *(const uint2*)&xw1h[(size_t)ss[q] * 128 + c * 4];
#pragma unroll
        for (int q = 0; q < 8; ++q) {
            const float2 f01 = __half22float2(*(const __half2*)&rv[q].x);
            const float2 f23 = __half22float2(*(const __half2*)&rv[q].y);
            acc0 = fmaf(ww[q], f01.x, acc0);
            acc1 = fmaf(ww[q], f01.y, acc1);
            acc2 = fmaf(ww[q], f23.x, acc2);
            acc3 = fmaf(ww[q], f23.y, acc3);
            dnm += ww[q];
        }
    }
    *(float4*)&racc[g][c * 4] = make_float4(acc0, acc1, acc2, acc3);
    if ((c & 7) == 0) rd[g][h] = dnm;        // one rep lane per (group,head)
    __syncthreads();
    const int j = t;                         // output feature
    const int h2 = j >> 5;
    const float tot = racc[0][j] + racc[1][j] + racc[2][j] + racc[3][j];
    const float dn = rd[0][h2] + rd[1][h2] + rd[2][h2] + rd[3][h2];
    const float hv = tot / dn + b1[j];
    out1h[(size_t)d * 128 + j] = __float2half(hv > 0.f ? hv : 0.f);  // bias+ReLU
}

// ---------------------------------------------------------------------------
// Layer 2 GEMM: 16 nodes/block, 256 threads. Reads fp16 out1, fp32 math,
// xw2 stored fp16, al2/ar2 fp32.
// ---------------------------------------------------------------------------
__global__ __launch_bounds__(256)
void k_gemm2(const __half* __restrict__ out1h, const float* __restrict__ W2,
             const float* __restrict__ a_src2, const float* __restrict__ a_dst2,
             __half* __restrict__ xw2h, float* __restrict__ al2, float* __restrict__ ar2) {
    const int t = threadIdx.x;
    const int node0 = blockIdx.x * 16;
    __shared__ float sW[128 * 16];
    __shared__ float sh[16][129];            // +1 pad: kills 4-way bank conflict
    for (int i = t; i < 2048; i += 256) sW[i] = W2[i];
    for (int i = t; i < 2048; i += 256) {
        const int nn = i >> 7, kk = i & 127;
        sh[nn][kk] = __half2float(out1h[(size_t)(node0 + nn) * 128 + kk]);
    }
    __syncthreads();
    const int nn = t >> 4;                   // 0..15
    const int j = t & 15;
    float acc = 0.f;
#pragma unroll 8
    for (int k = 0; k < 128; ++k)
        acc = fmaf(sh[nn][k], sW[k * 16 + j], acc);
    xw2h[(size_t)(node0 + nn) * 16 + j] = __float2half(acc);

    float ps = acc * a_src2[j];
    float pd = acc * a_dst2[j];
#pragma unroll
    for (int o = 8; o; o >>= 1) { ps += __shfl_xor(ps, o, 64); pd += __shfl_xor(pd, o, 64); }
    if (j == 0) { al2[node0 + nn] = ps; ar2[node0 + nn] = pd; }
}

// ---------------------------------------------------------------------------
// Layer 2 pull-aggregation: one wave per node; 8 edge-groups x 8 half2
// feature-lanes. Cross-group shuffle reduction, fused +b2.
// ---------------------------------------------------------------------------
__global__ __launch_bounds__(256)
void k_aggr2(const int* __restrict__ ssrc, const int* __restrict__ offs,
             const int* __restrict__ deg, const float* __restrict__ al2,
             const float* __restrict__ ar2, const __half* __restrict__ xw2h,
             const float* __restrict__ b2, float* __restrict__ out) {
    const int lane = threadIdx.x & 63;
    const int node = blockIdx.x * 4 + (threadIdx.x >> 6);
    const int j2 = lane & 7;                 // feature pair 2*j2, 2*j2+1
    const int eL = lane >> 3;                // 0..7
    const int beg = offs[node];
    const int n = deg[node];
    const float ard = ar2[node];
    float a0 = 0.f, a1 = 0.f, dnm = 0.f;
    for (int base = 0; base < n; base += 8) {
        const int e = base + eL;
        const bool p = e < n;
        const int s = ssrc[beg + (p ? e : 0)];
        float v = al2[s] + ard;
        v = v > 0.f ? v : NEG_SLOPE * v;
        const float w = p ? __expf(v) : 0.f;
        const float2 f = __half22float2(*(const __half2*)&xw2h[(size_t)s * 16 + j2 * 2]);
        a0 = fmaf(w, f.x, a0);
        a1 = fmaf(w, f.y, a1);
        dnm += w;
    }
#pragma unroll
    for (int o = 8; o < 64; o <<= 1) {
        a0 += __shfl_xor(a0, o, 64);
        a1 += __shfl_xor(a1, o, 64);
        dnm += __shfl_xor(dnm, o, 64);
    }
    if (eL == 0) {
        out[(size_t)node * 16 + j2 * 2]     = a0 / dnm + b2[j2 * 2];
        out[(size_t)node * 16 + j2 * 2 + 1] = a1 / dnm + b2[j2 * 2 + 1];
    }
}

extern "C" void kernel_launch(void* const* d_in, const int* in_sizes, int n_in,
                              void* d_out, int out_size, void* d_ws, size_t ws_size,
                              hipStream_t stream) {
    const float* x      = (const float*)d_in[0];
    const int*   ei     = (const int*)d_in[1];
    const float* W1     = (const float*)d_in[2];
    const float* a_src1 = (const float*)d_in[3];
    const float* a_dst1 = (const float*)d_in[4];
    const float* b1     = (const float*)d_in[5];
    const float* W2     = (const float*)d_in[6];
    const float* a_src2 = (const float*)d_in[7];
    const float* a_dst2 = (const float*)d_in[8];
    const float* b2     = (const float*)d_in[9];
    float* out = (float*)d_out;

    // Workspace (byte-addressed). Aliases:
    //  - pairs (13.6MB) sits in out1h's region (25.6MB): consumed by k_fill2
    //    before k_aggr1 writes out1h.
    //  - xw2h/al2/ar2 sit in xw1h's region: written by k_gemm2 after k_aggr1
    //    is done with xw1h.
    char* wsb = (char*)d_ws;
    __half* xw1h = (__half*)wsb;                                  // N*128 half (25.6 MB)
    __half* xw2h = (__half*)wsb;                                  // N*16 half (alias)
    float*  al2  = (float*)(wsb + (size_t)N_NODES * 16 * 2);      // N fp32 (alias)
    float*  ar2  = al2 + N_NODES;                                 // N fp32 (alias)
    __half* out1h = (__half*)(wsb + (size_t)N_NODES * 128 * 2);   // N*128 half (25.6 MB)
    int2*   pairs = (int2*)out1h;                                 // E_TOT int2 (alias)
    float*  al1  = (float*)(wsb + (size_t)N_NODES * 128 * 4);     // N*4 fp32
    float*  ar1  = al1 + (size_t)N_NODES * 4;                     // N*4
    int* ideg = (int*)(ar1 + (size_t)N_NODES * 4);                // N
    int* ioff = ideg + N_NODES;                                   // N
    int* icur = ioff + N_NODES;                                   // N
    int* ibs  = icur + N_NODES;                                   // 512
    int* ibcur = ibs + 512;                                       // 128
    int* isrc = ibcur + 128;                                      // E_TOT

    hipMemsetAsync(ideg, 0, (size_t)N_NODES * sizeof(int), stream);

    // CSR build (shared by both layers)
    k_hist<<<(E_TOT + 255) / 256, 256, 0, stream>>>(ei, ideg);
    k_scan1<<<NB1, 256, 0, stream>>>(ideg, ioff, ibs);
    k_scan2<<<1, 512, 0, stream>>>(ibs);
    k_scan3<<<NB1, 256, 0, stream>>>(ioff, ibs, icur, ibcur);
    k_part<<<(E_TOT + PART_EPB - 1) / PART_EPB, 256, 0, stream>>>(ei, ibcur, pairs);
    {   // grid padded to a multiple of 8 for the XCD swizzle
        int g = (E_TOT + 255) / 256;
        g = (g + 7) & ~7;
        k_fill2<<<g, 256, 0, stream>>>(pairs, icur, isrc);
    }

    // Layer 1
    k_gemm1<<<N_NODES / 32, 256, 0, stream>>>(x, W1, a_src1, a_dst1, xw1h, al1, ar1);
    k_aggr1<<<N_NODES, 128, 0, stream>>>(isrc, ioff, ideg, al1, ar1, xw1h, b1, out1h);

    // Layer 2
    k_gemm2<<<N_NODES / 16, 256, 0, stream>>>(out1h, W2, a_src2, a_dst2, xw2h, al2, ar2);
    k_aggr2<<<N_NODES / 4, 256, 0, stream>>>(isrc, ioff, ideg, al2, ar2, xw2h, b2, out);
}